// Round 12
// baseline (227.925 us; speedup 1.0000x reference)
//
#include <hip/hip_runtime.h>
#include <stdint.h>

typedef unsigned long long u64;

#define Bn 4
#define CINn 32
#define Hn 64
#define Wn 64
#define Sn 4096
#define KCn 32
#define Mn 16
#define COUTn 32
#define AREAn 9
#define Fn 288
#define NITER 10
#define FXSCALE 4294967296.0
#define NBLK_B 16          // k_main blocks per batch
#define PXB 256            // pixels per k_main block
#define CMAX 160           // max 32-px chunks per batch
#define LDK 292            // padded LDS row stride (floats) in k_out
#define NFLAG ((NITER + 3) * Bn * NBLK_B)   // +seg round

// Relaxed agent-scope atomics: coherent (complete at L3), zero cache-maint ops.
#define AT_LD_U32(p)    __hip_atomic_load((p),  __ATOMIC_RELAXED, __HIP_MEMORY_SCOPE_AGENT)
#define AT_LD_U64(p)    __hip_atomic_load((p),  __ATOMIC_RELAXED, __HIP_MEMORY_SCOPE_AGENT)
#define AT_ST_U32(p,v)  __hip_atomic_store((p), (v), __ATOMIC_RELAXED, __HIP_MEMORY_SCOPE_AGENT)
#define AT_ST_U64(p,v)  __hip_atomic_store((p), (v), __ATOMIC_RELAXED, __HIP_MEMORY_SCOPE_AGENT)

static __device__ __forceinline__ float relu_(float v){ return v > 0.f ? v : 0.f; }
static __device__ __forceinline__ float sigmoid_(float v){ return 1.f / (1.f + expf(-v)); }

// ---------------------------------------------------------------------------
// K0: feat = 3x3 mean; zero gsum (3 buffers) + gcnt + gpsum + flags.
// ---------------------------------------------------------------------------
__global__ __launch_bounds__(256) void k_init(const float* __restrict__ x,
                                              float* __restrict__ feat,
                                              u64* __restrict__ gsum,
                                              unsigned* __restrict__ gcnt,
                                              float* __restrict__ gpsum,
                                              unsigned* __restrict__ flags){
    int g = blockIdx.x * 256 + threadIdx.x;
    if (g < 3 * Bn * KCn * CINn) gsum[g] = 0ull;
    if (g < 3 * Bn * KCn)        gcnt[g] = 0u;
    if (g < Bn * KCn * Fn)       gpsum[g] = 0.f;
    if (g < NFLAG)               flags[g] = 0u;
    int p = g & (Sn - 1);
    int c = (g >> 12) & (CINn - 1);
    int b = g >> 17;
    int y = p >> 6, xx = p & 63;
    const float* xc = x + ((size_t)(b * CINn + c) << 12);
    float s = 0.f;
    #pragma unroll
    for (int i = 0; i < 3; ++i){
        int yy = y + i - 1;
        if (yy < 0 || yy >= Hn) continue;
        #pragma unroll
        for (int j = 0; j < 3; ++j){
            int xj = xx + j - 1;
            if (xj < 0 || xj >= Wn) continue;
            s += xc[(yy << 6) + xj];
        }
    }
    feat[g] = s * (1.f / 9.f);
}

// ---------------------------------------------------------------------------
// K1: fused pipeline. Grid = 64 blocks (4 batches x 16), 256 threads.
// r11-best exchange: per-address flags, atomicAdd publish into triple-buffered
// gsum, 8KB ILP readback. Balanced tile-run segmean (r8-r10 numerics).
// ---------------------------------------------------------------------------
struct AssignSh {
    float4 fvQ[8][PXB + 1];   // 32.1 KiB; pad kills 8-way bucket-walk conflicts
    float  f2L[PXB];
    float4 cent4[KCn][8];     // persists (empty-cluster keep, identical in all blocks)
    float  c2[KCn];
    float  bestdM[4][PXB];
    int    bestkM[4][PXB];
    unsigned lcnt[KCn];
    unsigned off32[KCn + 1];
    unsigned scat[KCn];
    unsigned cntPrev[KCn];
    int   plist[PXB];
    int   rankF[PXB];
    unsigned baseBT[KCn];
};
struct SmkSh {
    float psum[CINn][AREAn][8];
    float centL[Fn];
    int   spl[PXB];           // packed tile entries (k<<16|p)
    int   runK[33], runS[33], runE[33];
    int   nruns;
    float part1[16][16], part2[16][16];
    float hL[2][Mn];
    float kfL[2][Mn];
};
union ShU { AssignSh a; SmkSh m; };

__global__ __launch_bounds__(256) void k_main(const float* __restrict__ x,
        const float* __restrict__ feat,
        u64* __restrict__ gsum, unsigned* __restrict__ gcnt,
        unsigned* __restrict__ blkcnt,
        float* __restrict__ idxf,
        int* __restrict__ sorted, int4* __restrict__ chunk_map,
        const float* __restrict__ Wh1, const float* __restrict__ bh1,
        const float* __restrict__ Wh2, const float* __restrict__ bh2,
        const float* __restrict__ Wa,  const float* __restrict__ ba,
        const float* __restrict__ Wc,  const float* __restrict__ bc,
        const float* __restrict__ Wo,  const float* __restrict__ bo,
        const float* __restrict__ Wb1, const float* __restrict__ bb1,
        const float* __restrict__ Wb2, const float* __restrict__ bb2,
        const float* __restrict__ Wb3, const float* __restrict__ bb3,
        float* __restrict__ wcin, float* __restrict__ warea,
        float* __restrict__ wcout, float* __restrict__ biasb,
        float* __restrict__ gpsum,
        unsigned* __restrict__ flg){
    __shared__ int bi256[PXB];
    __shared__ unsigned totK[KCn];
    __shared__ unsigned goffK[KCn + 1];
    __shared__ unsigned chunkOff[KCn + 1];
    __shared__ ShU sh;

    const int tid  = threadIdx.x;
    const int b    = blockIdx.x >> 4;
    const int tnum = blockIdx.x & 15;
    const int p    = tnum * PXB + tid;
    const int kq   = tid >> 6;      // 0..3 (k-group of 8)
    const int pxb  = tid & 63;

    // ---- stage features: fvQ[cq][px] float4, + |f|^2 (both iter-invariant)
    float fv[CINn];
    #pragma unroll
    for (int cq = 0; cq < 8; ++cq){
        float4 v;
        v.x = feat[(b * CINn + cq * 4 + 0) * Sn + p];
        v.y = feat[(b * CINn + cq * 4 + 1) * Sn + p];
        v.z = feat[(b * CINn + cq * 4 + 2) * Sn + p];
        v.w = feat[(b * CINn + cq * 4 + 3) * Sn + p];
        sh.a.fvQ[cq][tid] = v;
        fv[cq * 4 + 0] = v.x; fv[cq * 4 + 1] = v.y;
        fv[cq * 4 + 2] = v.z; fv[cq * 4 + 3] = v.w;
    }
    {
        float s = 0.f;
        #pragma unroll
        for (int c = 0; c < CINn; ++c) s = fmaf(fv[c], fv[c], s);
        sh.a.f2L[tid] = s;
    }
    __syncthreads();

    // ---------------- KMeans iterations ----------------
    for (int iter = 0; iter <= NITER; ++iter){
        const int prev = (iter + 2) % 3;
        const int cur  = iter % 3;
        const int nxt  = (iter + 1) % 3;

        if (iter == 0){
            float* centf = (float*)sh.a.cent4;
            for (int e = tid; e < KCn * CINn; e += 256){
                int k = e >> 5, c = e & 31;
                centf[e] = feat[(b * CINn + c) * Sn + k * (Sn / KCn)];
            }
        } else {
            // poll 16 per-block flags of iter-1 in parallel (separate lines)
            if (tid < NBLK_B)
                while (AT_LD_U32(&flg[(iter - 1) * Bn * NBLK_B + b * NBLK_B + tid]) == 0u)
                    __builtin_amdgcn_s_sleep(2);
            __syncthreads();
            if (tid < KCn)
                sh.a.cntPrev[tid] = AT_LD_U32(&gcnt[(prev * Bn + b) * KCn + tid]);
        u64 sv[4];
            #pragma unroll
            for (int q = 0; q < 4; ++q)
                sv[q] = AT_LD_U64(&gsum[(size_t)(prev * Bn + b) * 1024 + tid + q * 256]);
            __syncthreads();
            float* centf = (float*)sh.a.cent4;
            #pragma unroll
            for (int q = 0; q < 4; ++q){
                const int e = tid + q * 256;
                unsigned cn = sh.a.cntPrev[e >> 5];
                if (cn > 0)
                    centf[e] = (float)((double)(long long)sv[q] / ((double)cn * FXSCALE));
                // cn==0: keep previous centroid (identical in every block)
            }
        }
        if (iter < NITER && tnum == (iter & 15)){   // rotate zero-owner
            for (int e = tid; e < KCn * CINn; e += 256)
                AT_ST_U64(&gsum[(size_t)(nxt * Bn + b) * 1024 + e], 0ull);
            if (tid < KCn) AT_ST_U32(&gcnt[(nxt * Bn + b) * KCn + tid], 0u);
        }
        __syncthreads();
        if (tid < KCn){
            const float4* cr = sh.a.cent4[tid];
            float s = 0.f;
            #pragma unroll
            for (int cq2 = 0; cq2 < 8; ++cq2){
                float4 v = cr[cq2];
                s = fmaf(v.x, v.x, s); s = fmaf(v.y, v.y, s);
                s = fmaf(v.z, v.z, s); s = fmaf(v.w, v.w, s);
            }
            sh.a.c2[tid] = s;
            sh.a.lcnt[tid] = 0u;
            sh.a.scat[tid] = 0u;
        }
        __syncthreads();

        // ---- register-tiled dots: thread = (kq, pxb) -> 4 px x 8 k ----
        float dot[4][8];
        #pragma unroll
        for (int j = 0; j < 4; ++j)
            #pragma unroll
            for (int kk = 0; kk < 8; ++kk) dot[j][kk] = 0.f;
        #pragma unroll
        for (int cq2 = 0; cq2 < 8; ++cq2){
            float4 fr0 = sh.a.fvQ[cq2][pxb];
            float4 fr1 = sh.a.fvQ[cq2][pxb + 64];
            float4 fr2 = sh.a.fvQ[cq2][pxb + 128];
            float4 fr3 = sh.a.fvQ[cq2][pxb + 192];
            #pragma unroll
            for (int kk = 0; kk < 8; ++kk){
                float4 cv = sh.a.cent4[kq * 8 + kk][cq2];
                dot[0][kk] = fmaf(fr0.x, cv.x, dot[0][kk]); dot[0][kk] = fmaf(fr0.y, cv.y, dot[0][kk]);
                dot[0][kk] = fmaf(fr0.z, cv.z, dot[0][kk]); dot[0][kk] = fmaf(fr0.w, cv.w, dot[0][kk]);
                dot[1][kk] = fmaf(fr1.x, cv.x, dot[1][kk]); dot[1][kk] = fmaf(fr1.y, cv.y, dot[1][kk]);
                dot[1][kk] = fmaf(fr1.z, cv.z, dot[1][kk]); dot[1][kk] = fmaf(fr1.w, cv.w, dot[1][kk]);
                dot[2][kk] = fmaf(fr2.x, cv.x, dot[2][kk]); dot[2][kk] = fmaf(fr2.y, cv.y, dot[2][kk]);
                dot[2][kk] = fmaf(fr2.z, cv.z, dot[2][kk]); dot[2][kk] = fmaf(fr2.w, cv.w, dot[2][kk]);
                dot[3][kk] = fmaf(fr3.x, cv.x, dot[3][kk]); dot[3][kk] = fmaf(fr3.y, cv.y, dot[3][kk]);
                dot[3][kk] = fmaf(fr3.z, cv.z, dot[3][kk]); dot[3][kk] = fmaf(fr3.w, cv.w, dot[3][kk]);
            }
        }
        #pragma unroll
        for (int j = 0; j < 4; ++j){
            const int px = pxb + 64 * j;
            const float f2v = sh.a.f2L[px];
            float bd = 3.402823466e38f; int bkk = kq * 8;
            #pragma unroll
            for (int kk = 0; kk < 8; ++kk){
                float d = f2v - 2.f * dot[j][kk] + sh.a.c2[kq * 8 + kk];
                if (d < bd){ bd = d; bkk = kq * 8 + kk; }   // strict < = first-min
            }
            sh.a.bestdM[kq][px] = bd;
            sh.a.bestkM[kq][px] = bkk;
        }
        __syncthreads();
        int bk;
        {
            float bd = sh.a.bestdM[0][tid]; bk = sh.a.bestkM[0][tid];
            #pragma unroll
            for (int q = 1; q < 4; ++q){
                float d2 = sh.a.bestdM[q][tid];
                if (d2 < bd){ bd = d2; bk = sh.a.bestkM[q][tid]; }  // tie -> lower k
            }
            bi256[tid] = bk;
        }

        if (iter < NITER){
            atomicAdd(&sh.a.lcnt[bk], 1u);
            __syncthreads();
            if (tid == 0){
                unsigned acc = 0;
                #pragma unroll
                for (int k = 0; k < KCn; ++k){ sh.a.off32[k] = acc; acc += sh.a.lcnt[k]; }
                sh.a.off32[KCn] = acc;
            }
            __syncthreads();
            {
                unsigned pos = sh.a.off32[bk] + atomicAdd(&sh.a.scat[bk], 1u);
                sh.a.plist[pos] = tid;   // in-cluster order irrelevant (sum commutes)
            }
            __syncthreads();
            {   // wave-parallel bucket sums -> device atomicAdd (16-way max)
                const int wv   = tid >> 6;
                const int lane = tid & 63;
                const int hf   = lane >> 5;
                const int c    = lane & 31;
                const float* fvf = (const float*)sh.a.fvQ;
                #pragma unroll
                for (int kq2 = 0; kq2 < 8; ++kq2){
                    const int k  = wv * 8 + kq2;
                    const int o0 = (int)sh.a.off32[k];
                    const int n  = (int)sh.a.off32[k + 1] - o0;
                    u64 acc = 0ull;
                    for (int i = hf; i < n; i += 2){
                        int px = sh.a.plist[o0 + i];
                        float fvv = fvf[(c >> 2) * 1028 + px * 4 + (c & 3)]; // padded stride
                        acc += (u64)llrint((double)fvv * FXSCALE);
                    }
                    acc += __shfl_down(acc, 32);
                    if (lane < 32 && n > 0)
                        atomicAdd(&gsum[(size_t)(cur * Bn + b) * 1024 + k * 32 + c], acc);
                }
            }
            if (tid < KCn){
                unsigned v = sh.a.lcnt[tid];
                if (v) atomicAdd(&gcnt[(cur * Bn + b) * KCn + tid], v);
            }
            __syncthreads();   // drains atomics (vmcnt(0) before barrier)
            if (tid == 0)
                AT_ST_U32(&flg[iter * Bn * NBLK_B + b * NBLK_B + tnum], 1u);
        } else {
            idxf[b * Sn + p] = (float)bk;       // output
            __syncthreads();
            if (tid < KCn){                     // stable in-block ranks + counts
                int r = 0;
                for (int q = 0; q < PXB; ++q)
                    if (bi256[q] == tid) sh.a.rankF[q] = r++;
                AT_ST_U32(&blkcnt[(b * KCn + tid) * NBLK_B + tnum], (unsigned)r);
            }
            __syncthreads();
            if (tid == 0)
                AT_ST_U32(&flg[NITER * Bn * NBLK_B + b * NBLK_B + tnum], 1u);
        }
    }

    // ---------------- distributed stable sort: scan + scatter ----------------
    if (tid < NBLK_B)
        while (AT_LD_U32(&flg[NITER * Bn * NBLK_B + b * NBLK_B + tid]) == 0u)
            __builtin_amdgcn_s_sleep(2);
    __syncthreads();
    if (tid < KCn){
        unsigned run = 0, mybase = 0;
        #pragma unroll 4
        for (int blk = 0; blk < NBLK_B; ++blk){
            unsigned v = AT_LD_U32(&blkcnt[(b * KCn + tid) * NBLK_B + blk]);
            if (blk == tnum) mybase = run;
            run += v;
        }
        totK[tid] = run;
        sh.a.baseBT[tid] = mybase;
    }
    __syncthreads();
    if (tid == 0){
        unsigned acc = 0;
        #pragma unroll
        for (int k = 0; k < KCn; ++k){ goffK[k] = acc; acc += totK[k]; }
        goffK[KCn] = acc;
    }
    __syncthreads();
    {
        int k = bi256[tid];
        unsigned pos = goffK[k] + sh.a.baseBT[k] + (unsigned)sh.a.rankF[tid];
        AT_ST_U32((unsigned*)&sorted[b * Sn + pos], (unsigned)(p | (k << 16)));
    }
    if (tnum == 0){                              // parallel chunk_map build
        if (tid == 0){
            unsigned acc = 0;
            #pragma unroll
            for (int k = 0; k < KCn; ++k){ chunkOff[k] = acc; acc += (totK[k] + 31) >> 5; }
            chunkOff[KCn] = acc;
        }
        __syncthreads();
        if (tid < KCn){
            int n = (int)totK[tid];
            unsigned j0 = chunkOff[tid];
            for (int cb = 0; cb < n; cb += 32)
                chunk_map[b * CMAX + (j0++)] = make_int4(tid, (int)goffK[tid] + cb, min(32, n - cb), 0);
        }
        for (int j = (int)chunkOff[KCn] + tid; j < CMAX; j += 256)
            chunk_map[b * CMAX + j] = make_int4(-1, 0, 0, 0);
    }
    __syncthreads();   // drain scatter stores
    if (tid == 0)
        AT_ST_U32(&flg[(NITER + 1) * Bn * NBLK_B + b * NBLK_B + tnum], 1u);
    if (tid < NBLK_B)
        while (AT_LD_U32(&flg[(NITER + 1) * Bn * NBLK_B + b * NBLK_B + tid]) == 0u)
            __builtin_amdgcn_s_sleep(2);
    __syncthreads();   // sorted complete; AssignSh dead -> union switches to sh.m

    // ---------------- segmean: balanced 256-entry tile per block ----------
    {
        sh.m.spl[tid] = (int)AT_LD_U32((unsigned*)&sorted[b * Sn + tnum * PXB + tid]);
        __syncthreads();
        if (tid == 0){
            int nr = 0, s0 = 0, kcur = sh.m.spl[0] >> 16;
            for (int i = 1; i < PXB; ++i){
                int kx = sh.m.spl[i] >> 16;
                if (kx != kcur){
                    sh.m.runK[nr] = kcur; sh.m.runS[nr] = s0; sh.m.runE[nr] = i;
                    ++nr; kcur = kx; s0 = i;
                }
            }
            sh.m.runK[nr] = kcur; sh.m.runS[nr] = s0; sh.m.runE[nr] = PXB;
            sh.m.nruns = nr + 1;
        }
        __syncthreads();
        const int cc = tid >> 3;
        const int sl = tid & 7;
        const float* xc = x + ((size_t)(b * CINn + cc) << 12);
        const int nruns = sh.m.nruns;
        for (int r = 0; r < nruns; ++r){
            const int ks = sh.m.runK[r];
            const int i0 = sh.m.runS[r], i1 = sh.m.runE[r];
            float acc[9];
            #pragma unroll
            for (int a = 0; a < 9; ++a) acc[a] = 0.f;
            for (int i = i0 + sl; i < i1; i += 8){
                int pp = sh.m.spl[i] & 0xFFFF;
                int py = pp >> 6, px2 = pp & 63;
                #pragma unroll
                for (int a = 0; a < 9; ++a){
                    int y1 = py + a / 3 - 1, x1 = px2 + (a % 3) - 1;
                    float v = (y1 >= 0 && y1 < Hn && x1 >= 0 && x1 < Wn)
                              ? xc[(y1 << 6) + x1] : 0.f;
                    acc[a] += v;
                }
            }
            #pragma unroll
            for (int a = 0; a < 9; ++a) sh.m.psum[cc][a][sl] = acc[a];
            __syncthreads();
            {
                int f = tid;
                int c = f / 9, a = f - c * 9;
                float sm = 0.f;
                #pragma unroll
                for (int s2 = 0; s2 < 8; ++s2) sm += sh.m.psum[c][a][s2];
                atomicAdd(&gpsum[((size_t)b * KCn + ks) * Fn + f], sm);
                if (tid < 32){
                    int f2i = 256 + tid;
                    int c2i = f2i / 9, a2i = f2i - c2i * 9;
                    float sm2 = 0.f;
                    #pragma unroll
                    for (int s2 = 0; s2 < 8; ++s2) sm2 += sh.m.psum[c2i][a2i][s2];
                    atomicAdd(&gpsum[((size_t)b * KCn + ks) * Fn + f2i], sm2);
                }
            }
            __syncthreads();
        }
    }
    __syncthreads();   // drain gpsum atomics
    if (tid == 0)
        AT_ST_U32(&flg[(NITER + 2) * Bn * NBLK_B + b * NBLK_B + tnum], 1u);
    if (tid < NBLK_B)
        while (AT_LD_U32(&flg[(NITER + 2) * Bn * NBLK_B + b * NBLK_B + tid]) == 0u)
            __builtin_amdgcn_s_sleep(2);
    __syncthreads();

    // -------- MLP + heads: clusters 2*tnum, 2*tnum+1 --------
    for (int kq2 = 0; kq2 < 2; ++kq2){
        const int kk = tnum * 2 + kq2;
        const float invn = 1.f / (float)max(totK[kk], 1u);
        __syncthreads();
        for (int f = tid; f < Fn; f += 256)
            sh.m.centL[f] = __uint_as_float(AT_LD_U32((unsigned*)&gpsum[((size_t)b * KCn + kk) * Fn + f])) * invn;
        __syncthreads();
        {
            int j = tid & 15, rep = tid >> 4;
            float p1 = 0.f, p2 = 0.f;
            int fbeg = rep * 18;
            for (int ff = fbeg; ff < fbeg + 18; ++ff){
                float cv = sh.m.centL[ff];
                p1 = fmaf(cv, Wh1[ff * Mn + j], p1);
                p2 = fmaf(cv, Wb1[ff * Mn + j], p2);
            }
            sh.m.part1[rep][j] = p1;
            sh.m.part2[rep][j] = p2;
        }
        __syncthreads();
        if (tid < 32){
            int br = tid >> 4, j = tid & 15;
            float s = br ? bb1[j] : bh1[j];
            for (int r = 0; r < 16; ++r) s += br ? sh.m.part2[r][j] : sh.m.part1[r][j];
            sh.m.hL[br][j] = relu_(s);
        }
        __syncthreads();
        if (tid < 32){
            int br = tid >> 4, j = tid & 15;
            const float* W2 = br ? Wb2 : Wh2;
            float s = br ? bb2[j] : bh2[j];
            #pragma unroll
            for (int i = 0; i < Mn; ++i) s = fmaf(sh.m.hL[br][i], W2[i * Mn + j], s);
            sh.m.kfL[br][j] = relu_(s);
        }
        __syncthreads();
        if (tid < 32){
            int o = tid;
            float s1 = bc[o], s2 = bo[o], s3 = bb3[o];
            #pragma unroll
            for (int i = 0; i < Mn; ++i){
                float kv = sh.m.kfL[0][i];
                s1 = fmaf(kv, Wc[i * COUTn + o], s1);
                s2 = fmaf(kv, Wo[i * COUTn + o], s2);
                s3 = fmaf(sh.m.kfL[1][i], Wb3[i * COUTn + o], s3);
            }
            wcin [(b * KCn + kk) * CINn  + o] = sigmoid_(s1);
            wcout[(b * KCn + kk) * COUTn + o] = sigmoid_(s2);
            biasb[(b * KCn + kk) * COUTn + o] = s3;
        } else if (tid < 41){
            int a2 = tid - 32;
            float s = ba[a2];
            #pragma unroll
            for (int i = 0; i < Mn; ++i) s = fmaf(sh.m.kfL[0][i], Wa[i * AREAn + a2], s);
            warea[(b * KCn + kk) * AREAn + a2] = sigmoid_(s);
        }
    }
}

// ---------------------------------------------------------------------------
// K2: grouped matmul, one 32-pixel single-cluster chunk per block.
// Bank-spread tiles: oA=o2, oB=o2+16; pxA=p2, pxB=p2+16 (2-way, free).
// ---------------------------------------------------------------------------
__global__ __launch_bounds__(256) void k_out(const float* __restrict__ x,
                                             const int* __restrict__ sorted,
                                             const int4* __restrict__ chunk_map,
                                             const float* __restrict__ wcin,
                                             const float* __restrict__ warea,
                                             const float* __restrict__ wcout,
                                             const float* __restrict__ biasb,
                                             const float* __restrict__ kern0,
                                             float* __restrict__ out){
    const int b   = blockIdx.x / CMAX;
    const int j   = blockIdx.x - b * CMAX;
    const int tid = threadIdx.x;

    int4 cm = chunk_map[b * CMAX + j];
    const int kcur = cm.x;
    if (kcur < 0) return;
    const int base = cm.y;
    const int cnt  = cm.z;

    __shared__ float kernT[COUTn * LDK];
    __shared__ float patchL[32 * LDK];
    __shared__ int   pix[32];
    __shared__ float wcl[CINn], wal[AREAn], wol[COUTn], biasL[COUTn];

    if (tid < 32){
        pix[tid] = (tid < cnt) ? (sorted[b * Sn + base + tid] & 0xFFFF) : -1;
    } else if (tid < 64)  wcl[tid - 32]    = wcin [(b * KCn + kcur) * CINn  + tid - 32];
    else if (tid < 96)    wol[tid - 64]    = wcout[(b * KCn + kcur) * COUTn + tid - 64];
    else if (tid < 105)   wal[tid - 96]    = warea[(b * KCn + kcur) * AREAn + tid - 96];
    else if (tid >= 128 && tid < 160) biasL[tid - 128] = biasb[(b * KCn + kcur) * COUTn + tid - 128];

    const int fA = tid;       const int cA = fA / 9, aA = fA - cA * 9;
    const int dyA = aA / 3 - 1, dxA = aA % 3 - 1;
    const int fB = 256 + tid; const int cB = fB / 9, aB = fB - cB * 9;
    const int dyB = aB / 3 - 1, dxB = aB % 3 - 1;
    __syncthreads();

    {   // build modulated kernel once
        int o  = tid >> 3;
        int q  = tid & 7;
        int f0 = q * 36;
        int cc = q * 4, aa = 0;
        float wo_ = wol[o];
        float* kr = kernT + o * LDK + f0;
        #pragma unroll 4
        for (int i2 = 0; i2 < 36; ++i2){
            kr[i2] = wcl[cc] * wal[aa] * wo_ * kern0[(f0 + i2) * COUTn + o];
            if (++aa == 9){ aa = 0; ++cc; }
        }
    }

    #pragma unroll 4
    for (int px = 0; px < 32; ++px){
        int pp = pix[px];
        float vA = 0.f, vB = 0.f;
        if (pp >= 0){
            int py = pp >> 6, pxx = pp & 63;
            int y1 = py + dyA, x1 = pxx + dxA;
            if (y1 >= 0 && y1 < Hn && x1 >= 0 && x1 < Wn)
                vA = x[((size_t)(b * CINn + cA) << 12) + (y1 << 6) + x1];
            if (tid < 32){
                int y2 = py + dyB, x2 = pxx + dxB;
                if (y2 >= 0 && y2 < Hn && x2 >= 0 && x2 < Wn)
                    vB = x[((size_t)(b * CINn + cB) << 12) + (y2 << 6) + x2];
            }
        }
        patchL[px * LDK + tid] = vA;
        if (tid < 32) patchL[px * LDK + 256 + tid] = vB;
    }
    __syncthreads();

    const int o2 = tid & 15, p2 = tid >> 4;
    const int oA = o2, oB = o2 + 16;
    const int pxA = p2, pxB = p2 + 16;
    const bool actA = pxA < cnt, actB = pxB < cnt;
    if (!actA && !actB) return;

    const float* krA = kernT + oA * LDK;
    const float* krB = kernT + oB * LDK;
    const float* prA = patchL + pxA * LDK;
    const float* prB = patchL + pxB * LDK;
    float s00 = 0.f, s01 = 0.f, s10 = 0.f, s11 = 0.f;
    #pragma unroll 4
    for (int fq = 0; fq < Fn; fq += 4){
        float4 k0 = *reinterpret_cast<const float4*>(krA + fq);
        float4 k1 = *reinterpret_cast<const float4*>(krB + fq);
        float4 pa = *reinterpret_cast<const float4*>(prA + fq);
        float4 pb = *reinterpret_cast<const float4*>(prB + fq);
        s00 = fmaf(pa.x,k0.x,s00); s00 = fmaf(pa.y,k0.y,s00); s00 = fmaf(pa.z,k0.z,s00); s00 = fmaf(pa.w,k0.w,s00);
        s01 = fmaf(pa.x,k1.x,s01); s01 = fmaf(pa.y,k1.y,s01); s01 = fmaf(pa.z,k1.z,s01); s01 = fmaf(pa.w,k1.w,s01);
        s10 = fmaf(pb.x,k0.x,s10); s10 = fmaf(pb.y,k0.y,s10); s10 = fmaf(pb.z,k0.z,s10); s10 = fmaf(pb.w,k0.w,s10);
        s11 = fmaf(pb.x,k1.x,s11); s11 = fmaf(pb.y,k1.y,s11); s11 = fmaf(pb.z,k1.z,s11); s11 = fmaf(pb.w,k1.w,s11);
    }
    if (actA){
        int pp = pix[pxA];
        out[((size_t)(b * COUTn + oA) << 12) + pp] = biasL[oA] + s00;
        out[((size_t)(b * COUTn + oB) << 12) + pp] = biasL[oB] + s01;
    }
    if (actB){
        int pp = pix[pxB];
        out[((size_t)(b * COUTn + oA) << 12) + pp] = biasL[oA] + s10;
        out[((size_t)(b * COUTn + oB) << 12) + pp] = biasL[oB] + s11;
    }
}

// ---------------------------------------------------------------------------
extern "C" void kernel_launch(void* const* d_in, const int* in_sizes, int n_in,
                              void* d_out, int out_size, void* d_ws, size_t ws_size,
                              hipStream_t stream){
    const float* x    = (const float*)d_in[0];
    const float* Wh1  = (const float*)d_in[1];
    const float* bh1  = (const float*)d_in[2];
    const float* Wh2  = (const float*)d_in[3];
    const float* bh2  = (const float*)d_in[4];
    const float* Wa   = (const float*)d_in[5];
    const float* ba   = (const float*)d_in[6];
    const float* Wc   = (const float*)d_in[7];
    const float* bc   = (const float*)d_in[8];
    const float* Wo   = (const float*)d_in[9];
    const float* bo   = (const float*)d_in[10];
    const float* kern0= (const float*)d_in[11];
    const float* Wb1  = (const float*)d_in[12];
    const float* bb1  = (const float*)d_in[13];
    const float* Wb2  = (const float*)d_in[14];
    const float* bb2  = (const float*)d_in[15];
    const float* Wb3  = (const float*)d_in[16];
    const float* bb3  = (const float*)d_in[17];

    char* ws = (char*)d_ws;
    float*    feat    = (float*)(ws + 0);             // 2,097,152
    u64*      gsum    = (u64*)  (ws + 2097152);       //    98,304 (3 buffers)
    unsigned* gcnt    = (unsigned*)(ws + 2195456);    //     1,536
    unsigned* blkcnt  = (unsigned*)(ws + 2196992);    //     8,192
    int*      sorted  = (int*)  (ws + 2205184);       //    65,536
    float*    gpsum   = (float*)(ws + 2270720);       //   147,456
    float*    wcin    = (float*)(ws + 2418176);       //    16,384
    float*    warea   = (float*)(ws + 2434560);       //     4,608
    float*    wcout   = (float*)(ws + 2439168);       //    16,384
    float*    biasb   = (float*)(ws + 2455552);       //    16,384
    int4*     chunk_map = (int4*)(ws + 2471936);      //    10,240
    unsigned* flags   = (unsigned*)(ws + 2482176);    //     4,096

    float* outp = (float*)d_out;
    float* idxf = outp + (size_t)Bn * COUTn * Sn;

    k_init<<<(Bn * CINn * Sn) / 256, 256, 0, stream>>>(x, feat, gsum, gcnt, gpsum, flags);
    k_main<<<Bn * NBLK_B, 256, 0, stream>>>(x, feat, gsum, gcnt, blkcnt, idxf,
                                            sorted, chunk_map,
                                            Wh1, bh1, Wh2, bh2, Wa, ba, Wc, bc, Wo, bo,
                                            Wb1, bb1, Wb2, bb2, Wb3, bb3,
                                            wcin, warea, wcout, biasb, gpsum, flags);
    k_out<<<Bn * CMAX, 256, 0, stream>>>(x, sorted, chunk_map, wcin, warea, wcout,
                                         biasb, kern0, outp);
}

// Round 13
// 217.010 us; speedup vs baseline: 1.0503x; 1.0503x over previous
//
#include <hip/hip_runtime.h>
#include <stdint.h>

typedef unsigned long long u64;

#define Bn 4
#define CINn 32
#define Hn 64
#define Wn 64
#define Sn 4096
#define KCn 32
#define Mn 16
#define COUTn 32
#define AREAn 9
#define Fn 288
#define NITER 10
#define FXSCALE 4294967296.0
#define NBLK_B 16          // k_main blocks per batch
#define PXB 256            // pixels per k_main block
#define CMAX 160           // max 32-px chunks per batch
#define LDK 292            // padded LDS row stride (floats) in k_out
#define NFLAG ((NITER + 2) * Bn * NBLK_B)

// Relaxed agent-scope atomics: coherent (complete at L3), zero cache-maint ops.
#define AT_LD_U32(p)    __hip_atomic_load((p),  __ATOMIC_RELAXED, __HIP_MEMORY_SCOPE_AGENT)
#define AT_LD_U64(p)    __hip_atomic_load((p),  __ATOMIC_RELAXED, __HIP_MEMORY_SCOPE_AGENT)
#define AT_ST_U32(p,v)  __hip_atomic_store((p), (v), __ATOMIC_RELAXED, __HIP_MEMORY_SCOPE_AGENT)
#define AT_ST_U64(p,v)  __hip_atomic_store((p), (v), __ATOMIC_RELAXED, __HIP_MEMORY_SCOPE_AGENT)

static __device__ __forceinline__ float relu_(float v){ return v > 0.f ? v : 0.f; }
static __device__ __forceinline__ float sigmoid_(float v){ return 1.f / (1.f + expf(-v)); }

// ---------------------------------------------------------------------------
// K0: feat = 3x3 mean; zero gsum (3 buffers) + gcnt + flags.
// ---------------------------------------------------------------------------
__global__ __launch_bounds__(256) void k_init(const float* __restrict__ x,
                                              float* __restrict__ feat,
                                              u64* __restrict__ gsum,
                                              unsigned* __restrict__ gcnt,
                                              unsigned* __restrict__ flags){
    int g = blockIdx.x * 256 + threadIdx.x;
    if (g < 3 * Bn * KCn * CINn) gsum[g] = 0ull;
    if (g < 3 * Bn * KCn)        gcnt[g] = 0u;
    if (g < NFLAG)               flags[g] = 0u;
    int p = g & (Sn - 1);
    int c = (g >> 12) & (CINn - 1);
    int b = g >> 17;
    int y = p >> 6, xx = p & 63;
    const float* xc = x + ((size_t)(b * CINn + c) << 12);
    float s = 0.f;
    #pragma unroll
    for (int i = 0; i < 3; ++i){
        int yy = y + i - 1;
        if (yy < 0 || yy >= Hn) continue;
        #pragma unroll
        for (int j = 0; j < 3; ++j){
            int xj = xx + j - 1;
            if (xj < 0 || xj >= Wn) continue;
            s += xc[(yy << 6) + xj];
        }
    }
    feat[g] = s * (1.f / 9.f);
}

// ---------------------------------------------------------------------------
// K1: fused pipeline. Grid = 64 blocks (4 batches x 16), 256 threads.
// Measured-best exchange: per-address flags, atomicAdd publish into
// triple-buffered gsum, 8KB ILP readback by every block.
// fvQ padded to [8][PXB+1]: bucket-walk row stride 1028 dwords -> 32 banks.
// ---------------------------------------------------------------------------
struct AssignSh {
    float4 fvQ[8][PXB + 1];   // 32.1 KiB [cq][px]; pad kills 8-way conflicts
    float  f2L[PXB];
    float4 cent4[KCn][8];     // persists (empty-cluster keep, identical in all blocks)
    float  c2[KCn];
    float  bestdM[4][PXB];
    int    bestkM[4][PXB];
    unsigned lcnt[KCn];
    unsigned off32[KCn + 1];
    unsigned scat[KCn];
    unsigned cntPrev[KCn];
    int   plist[PXB];
    int   rankF[PXB];
    unsigned baseBT[KCn];
};
struct SmkSh {
    float psum[CINn][AREAn][8];
    float centL[Fn];
    int   pl[256];
    float part1[16][16], part2[16][16];
    float hL[2][Mn];
    float kfL[2][Mn];
};
union ShU { AssignSh a; SmkSh m; };

__global__ __launch_bounds__(256) void k_main(const float* __restrict__ x,
        const float* __restrict__ feat,
        u64* __restrict__ gsum, unsigned* __restrict__ gcnt,
        unsigned* __restrict__ blkcnt,
        float* __restrict__ idxf,
        int* __restrict__ sorted, int4* __restrict__ chunk_map,
        const float* __restrict__ Wh1, const float* __restrict__ bh1,
        const float* __restrict__ Wh2, const float* __restrict__ bh2,
        const float* __restrict__ Wa,  const float* __restrict__ ba,
        const float* __restrict__ Wc,  const float* __restrict__ bc,
        const float* __restrict__ Wo,  const float* __restrict__ bo,
        const float* __restrict__ Wb1, const float* __restrict__ bb1,
        const float* __restrict__ Wb2, const float* __restrict__ bb2,
        const float* __restrict__ Wb3, const float* __restrict__ bb3,
        float* __restrict__ wcin, float* __restrict__ warea,
        float* __restrict__ wcout, float* __restrict__ biasb,
        unsigned* __restrict__ flg){
    __shared__ int bi256[PXB];
    __shared__ unsigned totK[KCn];
    __shared__ unsigned goffK[KCn + 1];
    __shared__ unsigned chunkOff[KCn + 1];
    __shared__ ShU sh;

    const int tid  = threadIdx.x;
    const int b    = blockIdx.x >> 4;
    const int tnum = blockIdx.x & 15;
    const int p    = tnum * PXB + tid;
    const int kq   = tid >> 6;      // 0..3 (k-group of 8)
    const int pxb  = tid & 63;

    // ---- stage features: fvQ[cq][px] float4, + |f|^2 (both iter-invariant)
    float fv[CINn];
    #pragma unroll
    for (int cq = 0; cq < 8; ++cq){
        float4 v;
        v.x = feat[(b * CINn + cq * 4 + 0) * Sn + p];
        v.y = feat[(b * CINn + cq * 4 + 1) * Sn + p];
        v.z = feat[(b * CINn + cq * 4 + 2) * Sn + p];
        v.w = feat[(b * CINn + cq * 4 + 3) * Sn + p];
        sh.a.fvQ[cq][tid] = v;
        fv[cq * 4 + 0] = v.x; fv[cq * 4 + 1] = v.y;
        fv[cq * 4 + 2] = v.z; fv[cq * 4 + 3] = v.w;
    }
    {
        float s = 0.f;
        #pragma unroll
        for (int c = 0; c < CINn; ++c) s = fmaf(fv[c], fv[c], s);
        sh.a.f2L[tid] = s;
    }
    __syncthreads();

    // ---------------- KMeans iterations ----------------
    for (int iter = 0; iter <= NITER; ++iter){
        const int prev = (iter + 2) % 3;
        const int cur  = iter % 3;
        const int nxt  = (iter + 1) % 3;

        if (iter == 0){
            float* centf = (float*)sh.a.cent4;
            for (int e = tid; e < KCn * CINn; e += 256){
                int k = e >> 5, c = e & 31;
                centf[e] = feat[(b * CINn + c) * Sn + k * (Sn / KCn)];
            }
        } else {
            // poll 16 per-block flags of iter-1 in parallel (separate lines ok)
            if (tid < NBLK_B)
                while (AT_LD_U32(&flg[(iter - 1) * Bn * NBLK_B + b * NBLK_B + tid]) == 0u)
                    __builtin_amdgcn_s_sleep(2);
            __syncthreads();
            if (tid < KCn)
                sh.a.cntPrev[tid] = AT_LD_U32(&gcnt[(prev * Bn + b) * KCn + tid]);
            u64 sv[4];
            #pragma unroll
            for (int q = 0; q < 4; ++q)
                sv[q] = AT_LD_U64(&gsum[(size_t)(prev * Bn + b) * 1024 + tid + q * 256]);
            __syncthreads();
            float* centf = (float*)sh.a.cent4;
            #pragma unroll
            for (int q = 0; q < 4; ++q){
                const int e = tid + q * 256;
                unsigned cn = sh.a.cntPrev[e >> 5];
                if (cn > 0)
                    centf[e] = (float)((double)(long long)sv[q] / ((double)cn * FXSCALE));
                // cn==0: keep previous centroid (identical in every block)
            }
        }
        if (iter < NITER && tnum == 0){
            for (int e = tid; e < KCn * CINn; e += 256)
                AT_ST_U64(&gsum[(size_t)(nxt * Bn + b) * 1024 + e], 0ull);
            if (tid < KCn) AT_ST_U32(&gcnt[(nxt * Bn + b) * KCn + tid], 0u);
        }
        __syncthreads();
        if (tid < KCn){
            const float4* cr = sh.a.cent4[tid];
            float s = 0.f;
            #pragma unroll
            for (int cq2 = 0; cq2 < 8; ++cq2){
                float4 v = cr[cq2];
                s = fmaf(v.x, v.x, s); s = fmaf(v.y, v.y, s);
                s = fmaf(v.z, v.z, s); s = fmaf(v.w, v.w, s);
            }
            sh.a.c2[tid] = s;
            sh.a.lcnt[tid] = 0u;
            sh.a.scat[tid] = 0u;
        }
        __syncthreads();

        // ---- register-tiled dots: thread = (kq, pxb) -> 4 px x 8 k ----
        float dot[4][8];
        #pragma unroll
        for (int j = 0; j < 4; ++j)
            #pragma unroll
            for (int kk = 0; kk < 8; ++kk) dot[j][kk] = 0.f;
        #pragma unroll
        for (int cq2 = 0; cq2 < 8; ++cq2){
            float4 fr0 = sh.a.fvQ[cq2][pxb];
            float4 fr1 = sh.a.fvQ[cq2][pxb + 64];
            float4 fr2 = sh.a.fvQ[cq2][pxb + 128];
            float4 fr3 = sh.a.fvQ[cq2][pxb + 192];
            #pragma unroll
            for (int kk = 0; kk < 8; ++kk){
                float4 cv = sh.a.cent4[kq * 8 + kk][cq2];
                dot[0][kk] = fmaf(fr0.x, cv.x, dot[0][kk]); dot[0][kk] = fmaf(fr0.y, cv.y, dot[0][kk]);
                dot[0][kk] = fmaf(fr0.z, cv.z, dot[0][kk]); dot[0][kk] = fmaf(fr0.w, cv.w, dot[0][kk]);
                dot[1][kk] = fmaf(fr1.x, cv.x, dot[1][kk]); dot[1][kk] = fmaf(fr1.y, cv.y, dot[1][kk]);
                dot[1][kk] = fmaf(fr1.z, cv.z, dot[1][kk]); dot[1][kk] = fmaf(fr1.w, cv.w, dot[1][kk]);
                dot[2][kk] = fmaf(fr2.x, cv.x, dot[2][kk]); dot[2][kk] = fmaf(fr2.y, cv.y, dot[2][kk]);
                dot[2][kk] = fmaf(fr2.z, cv.z, dot[2][kk]); dot[2][kk] = fmaf(fr2.w, cv.w, dot[2][kk]);
                dot[3][kk] = fmaf(fr3.x, cv.x, dot[3][kk]); dot[3][kk] = fmaf(fr3.y, cv.y, dot[3][kk]);
                dot[3][kk] = fmaf(fr3.z, cv.z, dot[3][kk]); dot[3][kk] = fmaf(fr3.w, cv.w, dot[3][kk]);
            }
        }
        #pragma unroll
        for (int j = 0; j < 4; ++j){
            const int px = pxb + 64 * j;
            const float f2v = sh.a.f2L[px];
            float bd = 3.402823466e38f; int bkk = kq * 8;
            #pragma unroll
            for (int kk = 0; kk < 8; ++kk){
                float d = f2v - 2.f * dot[j][kk] + sh.a.c2[kq * 8 + kk];
                if (d < bd){ bd = d; bkk = kq * 8 + kk; }   // strict < = first-min
            }
            sh.a.bestdM[kq][px] = bd;
            sh.a.bestkM[kq][px] = bkk;
        }
        __syncthreads();
        int bk;
        {
            float bd = sh.a.bestdM[0][tid]; bk = sh.a.bestkM[0][tid];
            #pragma unroll
            for (int q = 1; q < 4; ++q){
                float d2 = sh.a.bestdM[q][tid];
                if (d2 < bd){ bd = d2; bk = sh.a.bestkM[q][tid]; }  // tie -> lower k
            }
            bi256[tid] = bk;
        }

        if (iter < NITER){
            atomicAdd(&sh.a.lcnt[bk], 1u);
            __syncthreads();
            if (tid == 0){
                unsigned acc = 0;
                #pragma unroll
                for (int k = 0; k < KCn; ++k){ sh.a.off32[k] = acc; acc += sh.a.lcnt[k]; }
                sh.a.off32[KCn] = acc;
            }
            __syncthreads();
            {
                unsigned pos = sh.a.off32[bk] + atomicAdd(&sh.a.scat[bk], 1u);
                sh.a.plist[pos] = tid;   // in-cluster order irrelevant (sum commutes)
            }
            __syncthreads();
            {   // wave-parallel bucket sums -> device atomicAdd (16-way max)
                const int wv   = tid >> 6;
                const int lane = tid & 63;
                const int hf   = lane >> 5;
                const int c    = lane & 31;
                const float* fvf = (const float*)sh.a.fvQ;
                #pragma unroll
                for (int kq2 = 0; kq2 < 8; ++kq2){
                    const int k  = wv * 8 + kq2;
                    const int o0 = (int)sh.a.off32[k];
                    const int n  = (int)sh.a.off32[k + 1] - o0;
                    u64 acc = 0ull;
                    for (int i = hf; i < n; i += 2){
                        int px = sh.a.plist[o0 + i];
                        // padded row stride 1028 dwords -> banks cover all 32
                        float fvv = fvf[(c >> 2) * 1028 + px * 4 + (c & 3)];
                        acc += (u64)llrint((double)fvv * FXSCALE);
                    }
                    acc += __shfl_down(acc, 32);
                    if (lane < 32 && n > 0)
                        atomicAdd(&gsum[(size_t)(cur * Bn + b) * 1024 + k * 32 + c], acc);
                }
            }
            if (tid < KCn){
                unsigned v = sh.a.lcnt[tid];
                if (v) atomicAdd(&gcnt[(cur * Bn + b) * KCn + tid], v);
            }
            __syncthreads();   // drains atomics (vmcnt(0) before barrier)
            if (tid == 0)
                AT_ST_U32(&flg[iter * Bn * NBLK_B + b * NBLK_B + tnum], 1u);
        } else {
            idxf[b * Sn + p] = (float)bk;       // output
            __syncthreads();
            if (tid < KCn){                     // stable in-block ranks + counts
                int r = 0;
                for (int q = 0; q < PXB; ++q)
                    if (bi256[q] == tid) sh.a.rankF[q] = r++;
                AT_ST_U32(&blkcnt[(b * KCn + tid) * NBLK_B + tnum], (unsigned)r);
            }
            __syncthreads();
            if (tid == 0)
                AT_ST_U32(&flg[NITER * Bn * NBLK_B + b * NBLK_B + tnum], 1u);
        }
    }

    // ---------------- distributed stable sort: scan + scatter ----------------
    if (tid < NBLK_B)
        while (AT_LD_U32(&flg[NITER * Bn * NBLK_B + b * NBLK_B + tid]) == 0u)
            __builtin_amdgcn_s_sleep(2);
    __syncthreads();
    if (tid < KCn){
        unsigned run = 0, mybase = 0;
        #pragma unroll 4
        for (int blk = 0; blk < NBLK_B; ++blk){
            unsigned v = AT_LD_U32(&blkcnt[(b * KCn + tid) * NBLK_B + blk]);
            if (blk == tnum) mybase = run;
            run += v;
        }
        totK[tid] = run;
        sh.a.baseBT[tid] = mybase;
    }
    __syncthreads();
    if (tid == 0){
        unsigned acc = 0;
        #pragma unroll
        for (int k = 0; k < KCn; ++k){ goffK[k] = acc; acc += totK[k]; }
        goffK[KCn] = acc;
    }
    __syncthreads();
    {
        int k = bi256[tid];
        unsigned pos = goffK[k] + sh.a.baseBT[k] + (unsigned)sh.a.rankF[tid];
        AT_ST_U32((unsigned*)&sorted[b * Sn + pos], (unsigned)p);
    }
    if (tnum == 0){                              // parallel chunk_map build
        if (tid == 0){
            unsigned acc = 0;
            #pragma unroll
            for (int k = 0; k < KCn; ++k){ chunkOff[k] = acc; acc += (totK[k] + 31) >> 5; }
            chunkOff[KCn] = acc;
        }
        __syncthreads();
        if (tid < KCn){
            int n = (int)totK[tid];
            unsigned j0 = chunkOff[tid];
            for (int cb = 0; cb < n; cb += 32)
                chunk_map[b * CMAX + (j0++)] = make_int4(tid, (int)goffK[tid] + cb, min(32, n - cb), 0);
        }
        for (int j = (int)chunkOff[KCn] + tid; j < CMAX; j += 256)
            chunk_map[b * CMAX + j] = make_int4(-1, 0, 0, 0);
    }
    __syncthreads();   // drain scatter stores
    if (tid == 0)
        AT_ST_U32(&flg[(NITER + 1) * Bn * NBLK_B + b * NBLK_B + tnum], 1u);
    if (tid < NBLK_B)
        while (AT_LD_U32(&flg[(NITER + 1) * Bn * NBLK_B + b * NBLK_B + tid]) == 0u)
            __builtin_amdgcn_s_sleep(2);
    __syncthreads();   // sorted complete; AssignSh dead -> union switches to sh.m

    // -------- segmean + MLP + heads: clusters 2*tnum, 2*tnum+1 --------
    for (int kq2 = 0; kq2 < 2; ++kq2){
        const int kk   = tnum * 2 + kq2;
        const int off0 = (int)goffK[kk];
        const int nmy  = (int)totK[kk];
        __syncthreads();
        {
            const int cA = tid >> 3;
            const int s  = tid & 7;
            const float* xc = x + ((size_t)(b * CINn + cA) << 12);
            float acc[9];
            #pragma unroll
            for (int a = 0; a < 9; ++a) acc[a] = 0.f;
            for (int base = 0; base < nmy; base += 256){
                int m = min(256, nmy - base);
                __syncthreads();
                if (tid < m)
                    sh.m.pl[tid] = (int)AT_LD_U32((unsigned*)&sorted[b * Sn + off0 + base + tid]);
                __syncthreads();
                #pragma unroll 2
                for (int i = s; i < m; i += 8){
                    int pp = sh.m.pl[i];
                    int py = pp >> 6, px2 = pp & 63;
                    #pragma unroll
                    for (int a = 0; a < 9; ++a){
                        int y1 = py + a / 3 - 1, x1 = px2 + (a % 3) - 1;
                        float v = (y1 >= 0 && y1 < Hn && x1 >= 0 && x1 < Wn)
                                  ? xc[(y1 << 6) + x1] : 0.f;
                        acc[a] += v;
                    }
                }
            }
            __syncthreads();
            #pragma unroll
            for (int a = 0; a < 9; ++a) sh.m.psum[cA][a][s] = acc[a];
            __syncthreads();
            float invn = 1.f / (float)max(nmy, 1);
            for (int f = tid; f < Fn; f += 256){
                int c = f / 9, a = f - c * 9;
                float sm = 0.f;
                #pragma unroll
                for (int s2 = 0; s2 < 8; ++s2) sm += sh.m.psum[c][a][s2];
                sh.m.centL[f] = sm * invn;
            }
        }
        __syncthreads();
        {
            int j = tid & 15, rep = tid >> 4;
            float p1 = 0.f, p2 = 0.f;
            int fbeg = rep * 18;
            for (int ff = fbeg; ff < fbeg + 18; ++ff){
                float cv = sh.m.centL[ff];
                p1 = fmaf(cv, Wh1[ff * Mn + j], p1);
                p2 = fmaf(cv, Wb1[ff * Mn + j], p2);
            }
            sh.m.part1[rep][j] = p1;
            sh.m.part2[rep][j] = p2;
        }
        __syncthreads();
        if (tid < 32){
            int br = tid >> 4, j = tid & 15;
            float s = br ? bb1[j] : bh1[j];
            for (int r = 0; r < 16; ++r) s += br ? sh.m.part2[r][j] : sh.m.part1[r][j];
            sh.m.hL[br][j] = relu_(s);
        }
        __syncthreads();
        if (tid < 32){
            int br = tid >> 4, j = tid & 15;
            const float* W2 = br ? Wb2 : Wh2;
            float s = br ? bb2[j] : bh2[j];
            #pragma unroll
            for (int i = 0; i < Mn; ++i) s = fmaf(sh.m.hL[br][i], W2[i * Mn + j], s);
            sh.m.kfL[br][j] = relu_(s);
        }
        __syncthreads();
        if (tid < 32){
            int o = tid;
            float s1 = bc[o], s2 = bo[o], s3 = bb3[o];
            #pragma unroll
            for (int i = 0; i < Mn; ++i){
                float kv = sh.m.kfL[0][i];
                s1 = fmaf(kv, Wc[i * COUTn + o], s1);
                s2 = fmaf(kv, Wo[i * COUTn + o], s2);
                s3 = fmaf(sh.m.kfL[1][i], Wb3[i * COUTn + o], s3);
            }
            wcin [(b * KCn + kk) * CINn  + o] = sigmoid_(s1);
            wcout[(b * KCn + kk) * COUTn + o] = sigmoid_(s2);
            biasb[(b * KCn + kk) * COUTn + o] = s3;
        } else if (tid < 41){
            int a2 = tid - 32;
            float s = ba[a2];
            #pragma unroll
            for (int i = 0; i < Mn; ++i) s = fmaf(sh.m.kfL[0][i], Wa[i * AREAn + a2], s);
            warea[(b * KCn + kk) * AREAn + a2] = sigmoid_(s);
        }
    }
}

// ---------------------------------------------------------------------------
// K2: grouped matmul, one 32-pixel single-cluster chunk per block.
// Bank-spread tiles: oA=o2, oB=o2+16; pxA=p2, pxB=p2+16 (2-way, free).
// ---------------------------------------------------------------------------
__global__ __launch_bounds__(256) void k_out(const float* __restrict__ x,
                                             const int* __restrict__ sorted,
                                             const int4* __restrict__ chunk_map,
                                             const float* __restrict__ wcin,
                                             const float* __restrict__ warea,
                                             const float* __restrict__ wcout,
                                             const float* __restrict__ biasb,
                                             const float* __restrict__ kern0,
                                             float* __restrict__ out){
    const int b   = blockIdx.x / CMAX;
    const int j   = blockIdx.x - b * CMAX;
    const int tid = threadIdx.x;

    int4 cm = chunk_map[b * CMAX + j];
    const int kcur = cm.x;
    if (kcur < 0) return;
    const int base = cm.y;
    const int cnt  = cm.z;

    __shared__ float kernT[COUTn * LDK];
    __shared__ float patchL[32 * LDK];
    __shared__ int   pix[32];
    __shared__ float wcl[CINn], wal[AREAn], wol[COUTn], biasL[COUTn];

    if (tid < 32){
        pix[tid] = (tid < cnt) ? sorted[b * Sn + base + tid] : -1;
    } else if (tid < 64)  wcl[tid - 32]    = wcin [(b * KCn + kcur) * CINn  + tid - 32];
    else if (tid < 96)    wol[tid - 64]    = wcout[(b * KCn + kcur) * COUTn + tid - 64];
    else if (tid < 105)   wal[tid - 96]    = warea[(b * KCn + kcur) * AREAn + tid - 96];
    else if (tid >= 128 && tid < 160) biasL[tid - 128] = biasb[(b * KCn + kcur) * COUTn + tid - 128];

    const int fA = tid;       const int cA = fA / 9, aA = fA - cA * 9;
    const int dyA = aA / 3 - 1, dxA = aA % 3 - 1;
    const int fB = 256 + tid; const int cB = fB / 9, aB = fB - cB * 9;
    const int dyB = aB / 3 - 1, dxB = aB % 3 - 1;
    __syncthreads();

    {   // build modulated kernel once
        int o  = tid >> 3;
        int q  = tid & 7;
        int f0 = q * 36;
        int cc = q * 4, aa = 0;
        float wo_ = wol[o];
        float* kr = kernT + o * LDK + f0;
        #pragma unroll 4
        for (int i2 = 0; i2 < 36; ++i2){
            kr[i2] = wcl[cc] * wal[aa] * wo_ * kern0[(f0 + i2) * COUTn + o];
            if (++aa == 9){ aa = 0; ++cc; }
        }
    }

    #pragma unroll 4
    for (int px = 0; px < 32; ++px){
        int pp = pix[px];
        float vA = 0.f, vB = 0.f;
        if (pp >= 0){
            int py = pp >> 6, pxx = pp & 63;
            int y1 = py + dyA, x1 = pxx + dxA;
            if (y1 >= 0 && y1 < Hn && x1 >= 0 && x1 < Wn)
                vA = x[((size_t)(b * CINn + cA) << 12) + (y1 << 6) + x1];
            if (tid < 32){
                int y2 = py + dyB, x2 = pxx + dxB;
                if (y2 >= 0 && y2 < Hn && x2 >= 0 && x2 < Wn)
                    vB = x[((size_t)(b * CINn + cB) << 12) + (y2 << 6) + x2];
            }
        }
        patchL[px * LDK + tid] = vA;
        if (tid < 32) patchL[px * LDK + 256 + tid] = vB;
    }
    __syncthreads();

    const int o2 = tid & 15, p2 = tid >> 4;
    const int oA = o2, oB = o2 + 16;
    const int pxA = p2, pxB = p2 + 16;
    const bool actA = pxA < cnt, actB = pxB < cnt;
    if (!actA && !actB) return;

    const float* krA = kernT + oA * LDK;
    const float* krB = kernT + oB * LDK;
    const float* prA = patchL + pxA * LDK;
    const float* prB = patchL + pxB * LDK;
    float s00 = 0.f, s01 = 0.f, s10 = 0.f, s11 = 0.f;
    #pragma unroll 4
    for (int fq = 0; fq < Fn; fq += 4){
        float4 k0 = *reinterpret_cast<const float4*>(krA + fq);
        float4 k1 = *reinterpret_cast<const float4*>(krB + fq);
        float4 pa = *reinterpret_cast<const float4*>(prA + fq);
        float4 pb = *reinterpret_cast<const float4*>(prB + fq);
        s00 = fmaf(pa.x,k0.x,s00); s00 = fmaf(pa.y,k0.y,s00); s00 = fmaf(pa.z,k0.z,s00); s00 = fmaf(pa.w,k0.w,s00);
        s01 = fmaf(pa.x,k1.x,s01); s01 = fmaf(pa.y,k1.y,s01); s01 = fmaf(pa.z,k1.z,s01); s01 = fmaf(pa.w,k1.w,s01);
        s10 = fmaf(pb.x,k0.x,s10); s10 = fmaf(pb.y,k0.y,s10); s10 = fmaf(pb.z,k0.z,s10); s10 = fmaf(pb.w,k0.w,s10);
        s11 = fmaf(pb.x,k1.x,s11); s11 = fmaf(pb.y,k1.y,s11); s11 = fmaf(pb.z,k1.z,s11); s11 = fmaf(pb.w,k1.w,s11);
    }
    if (actA){
        int pp = pix[pxA];
        out[((size_t)(b * COUTn + oA) << 12) + pp] = biasL[oA] + s00;
        out[((size_t)(b * COUTn + oB) << 12) + pp] = biasL[oB] + s01;
    }
    if (actB){
        int pp = pix[pxB];
        out[((size_t)(b * COUTn + oA) << 12) + pp] = biasL[oA] + s10;
        out[((size_t)(b * COUTn + oB) << 12) + pp] = biasL[oB] + s11;
    }
}

// ---------------------------------------------------------------------------
extern "C" void kernel_launch(void* const* d_in, const int* in_sizes, int n_in,
                              void* d_out, int out_size, void* d_ws, size_t ws_size,
                              hipStream_t stream){
    const float* x    = (const float*)d_in[0];
    const float* Wh1  = (const float*)d_in[1];
    const float* bh1  = (const float*)d_in[2];
    const float* Wh2  = (const float*)d_in[3];
    const float* bh2  = (const float*)d_in[4];
    const float* Wa   = (const float*)d_in[5];
    const float* ba   = (const float*)d_in[6];
    const float* Wc   = (const float*)d_in[7];
    const float* bc   = (const float*)d_in[8];
    const float* Wo   = (const float*)d_in[9];
    const float* bo   = (const float*)d_in[10];
    const float* kern0= (const float*)d_in[11];
    const float* Wb1  = (const float*)d_in[12];
    const float* bb1  = (const float*)d_in[13];
    const float* Wb2  = (const float*)d_in[14];
    const float* bb2  = (const float*)d_in[15];
    const float* Wb3  = (const float*)d_in[16];
    const float* bb3  = (const float*)d_in[17];

    char* ws = (char*)d_ws;
    float*    feat    = (float*)(ws + 0);             // 2,097,152
    u64*      gsum    = (u64*)  (ws + 2097152);       //    98,304 (3 buffers)
    unsigned* gcnt    = (unsigned*)(ws + 2195456);    //     1,536
    unsigned* blkcnt  = (unsigned*)(ws + 2196992);    //     8,192
    int*      sorted  = (int*)  (ws + 2205184);       //    65,536
    float*    wcin    = (float*)(ws + 2270720);       //    16,384
    float*    warea   = (float*)(ws + 2287104);       //     4,608
    float*    wcout   = (float*)(ws + 2291712);       //    16,384
    float*    biasb   = (float*)(ws + 2308096);       //    16,384
    int4*     chunk_map = (int4*)(ws + 2324480);      //    10,240
    unsigned* flags   = (unsigned*)(ws + 2334720);    //     3,072

    float* outp = (float*)d_out;
    float* idxf = outp + (size_t)Bn * COUTn * Sn;

    k_init<<<(Bn * CINn * Sn) / 256, 256, 0, stream>>>(x, feat, gsum, gcnt, flags);
    k_main<<<Bn * NBLK_B, 256, 0, stream>>>(x, feat, gsum, gcnt, blkcnt, idxf,
                                            sorted, chunk_map,
                                            Wh1, bh1, Wh2, bh2, Wa, ba, Wc, bc, Wo, bo,
                                            Wb1, bb1, Wb2, bb2, Wb3, bb3,
                                            wcin, warea, wcout, biasb, flags);
    k_out<<<Bn * CMAX, 256, 0, stream>>>(x, sorted, chunk_map, wcin, warea, wcout,
                                         biasb, kern0, outp);
}